// Round 6
// baseline (380.325 us; speedup 1.0000x reference)
//
#include <hip/hip_runtime.h>
#include <cmath>

#define EPSF 1e-5f

// ---------------------------------------------------------------------------
// ws float layout:
//   W2F = ws      : float4[15][7][45] folded stage-2 conv weights, expert
//                   innermost.  Slot k=25 = folded bias; slots k=26/27 hold
//                   fcb2[e][0]/fcb2[e][1] for o==0 (0 elsewhere).
//   FC2 = +18900  : float4[2][15][45] fcw2 re-laid (expert innermost)
//   W1F = +24300  : float[20][9] folded stage-1 conv weights
//   B1F = +24480  : float[20]   folded stage-1 bias
// total 24500 floats (~98 KB)
// ---------------------------------------------------------------------------
#define OFF_FC2 18900
#define OFF_W1F 24300
#define OFF_B1F 24480

__global__ __launch_bounds__(256) void setup_tables(
    const float* __restrict__ w1, const float* __restrict__ b1,
    const float* __restrict__ g1, const float* __restrict__ be1,
    const float* __restrict__ m1, const float* __restrict__ v1,
    const float* __restrict__ w2, const float* __restrict__ b2,
    const float* __restrict__ g2, const float* __restrict__ be2,
    const float* __restrict__ m2, const float* __restrict__ v2,
    const float* __restrict__ fcw2, const float* __restrict__ fcb2,
    float* __restrict__ ws)
{
  const int t  = blockIdx.x * blockDim.x + threadIdx.x;
  const int nt = gridDim.x * blockDim.x;
  float* W2F = ws;
  float* FC2 = ws + OFF_FC2;
  float* W1F = ws + OFF_W1F;
  float* B1F = ws + OFF_B1F;

  for (int idx = t; idx < 18900; idx += nt) {
    int kk = idx & 3, rest = idx >> 2;
    int e = rest % 45, ok4 = rest / 45;
    int k4 = ok4 % 7, o = ok4 / 7;
    int k = k4 * 4 + kk;
    float s = g2[e*15+o] / sqrtf(v2[e*15+o] + EPSF);
    float v;
    if (k < 25)       v = w2[(e*15+o)*25 + k] * s;
    else if (k == 25) v = b2[e*15+o]*s + be2[e*15+o] - m2[e*15+o]*s;
    else if (k == 26) v = (o == 0) ? fcb2[e*2 + 0] : 0.0f;
    else              v = (o == 0) ? fcb2[e*2 + 1] : 0.0f;
    W2F[idx] = v;
  }
  for (int idx = t; idx < 5400; idx += nt) {
    int kk = idx & 3, rest = idx >> 2;
    int e = rest % 45, t2 = rest / 45;
    int f4 = t2 % 15, oo = t2 / 15;
    FC2[idx] = fcw2[(e*2+oo)*60 + f4*4 + kk];
  }
  for (int idx = t; idx < 180; idx += nt) {
    int ch = idx / 9;
    float s = g1[ch] / sqrtf(v1[ch] + EPSF);
    W1F[idx] = w1[idx] * s;
  }
  for (int idx = t; idx < 20; idx += nt) {
    float s = g1[idx] / sqrtf(v1[idx] + EPSF);
    B1F[idx] = b1[idx]*s + be1[idx] - m1[idx]*s;
  }
}

// component access into float4 array with compile-time index (after unroll)
#define GETC(arr, k) ((k)%4==0 ? arr[(k)/4].x : (k)%4==1 ? arr[(k)/4].y : \
                      (k)%4==2 ? arr[(k)/4].z : arr[(k)/4].w)

// ---------------------------------------------------------------------------
// 1 thread = 1 sample (round-5 post-mortem: with per-sample threads ALL
// stage-1 table indices are wave-uniform -> compiler emits s_load through
// the scalar cache: zero LDS / vector-mem cost for weights.  The 4-part
// splits made those reads lane-dependent ds_read_b128s = ~25 us of per-CU
// LDS-pipe serialization, and split registers to no benefit).
// 1024 waves total = 1 wave/SIMD: every stall must be prefetchable ->
//   * x staged via coalesced chunk loop (reg-staged, loads for chunk c+1
//     issued before downscale of chunk c hides HBM latency)
//   * stage-1 weights: s_load (scalar cache)
//   * stage-2 expert gathers: one-ahead prefetch (wv/fa/fb), bias packed
//     into W2F slot 25, fcb2 into slots 26/27 of o==0.
// Numerics: compute phases replicate R0's exact loop structure/order
// (known-passing absmax).
//
// Block = 128 threads = 128 samples; grid 512.  LDS 14112 floats (56.4 KB)
// -> 2 blocks/CU (4 waves/CU):
//   [0, 8704)     xds: 128 samples x 68-float stride (8x8 tile at sl*68)
//   [8704, 14112) RAW: 8-sample chunk staging, stride 169 float4
//                 -- dead after staging; reused for out staging
// ---------------------------------------------------------------------------
#define NS     128            // samples per block
#define CHS    8              // samples per chunk
#define NCH    (NS/CHS)       // 16 chunks
#define T_RAW  8704           // floats
#define SSTR4  169            // per-sample stride in RAW, float4 units

__global__ __launch_bounds__(128, 1) void fused_k(
    const float* __restrict__ x,
    const float* __restrict__ ws,
    const float* __restrict__ fcw1, const float* __restrict__ fcb1,
    float* __restrict__ out, int B)
{
  __shared__ float lds[14112];

  const int t  = threadIdx.x;
  const int B0 = blockIdx.x * NS;

  const float* W1F = ws + OFF_W1F;
  const float* B1F = ws + OFF_B1F;

  // ---- staging mapping: chunk of 8 samples, 16 threads per sample ----
  const int cs = t >> 4;       // sample-in-chunk 0..7
  const int ti = t & 15;       // loads float4 ti+16k
  const float4* xg = reinterpret_cast<const float4*>(x);
  float4* RAW4 = reinterpret_cast<float4*>(&lds[T_RAW]);

  // prologue: load chunk 0 into registers (rows 0..23 = 168 float4/sample)
  float4 pre[11];
  {
    const size_t bs = (size_t)(B0 + cs);
    #pragma unroll
    for (int k = 0; k < 11; k++) {
      const int q = ti + 16*k;
      if (q < 168 && (int)bs < B) pre[k] = xg[bs*196 + q];
    }
  }

  #pragma unroll 1
  for (int c = 0; c < NCH; c++) {
    __syncthreads();                  // prior chunk's RAW reads complete
    #pragma unroll
    for (int k = 0; k < 11; k++) {
      const int q = ti + 16*k;
      if (q < 168) RAW4[cs*SSTR4 + q] = pre[k];
    }
    if (c < NCH-1) {                  // issue next chunk's loads early
      const size_t bs = (size_t)(B0 + (c+1)*CHS + cs);
      #pragma unroll
      for (int k = 0; k < 11; k++) {
        const int q = ti + 16*k;
        if (q < 168 && (int)bs < B) pre[k] = xg[bs*196 + q];
      }
    }
    __syncthreads();                  // RAW(c) visible
    // downscale: thread (cs, orow=ti>>1, cp=ti&1) -> xd[orow][4cp..4cp+3]
    {
      const int orow = ti >> 1, cp = ti & 1;
      float a0 = 0.f, a1 = 0.f, a2 = 0.f, a3 = 0.f;
      #pragma unroll
      for (int dr = 0; dr < 3; dr++) {
        const float4* rp = reinterpret_cast<const float4*>(
            &lds[T_RAW + cs*SSTR4*4 + (3*orow + dr)*28 + 12*cp]);
        float4 q0 = rp[0], q1 = rp[1], q2 = rp[2];
        a0 += q0.x + q0.y + q0.z;
        a1 += q0.w + q1.x + q1.y;
        a2 += q1.z + q1.w + q2.x;
        a3 += q2.y + q2.z + q2.w;
      }
      float4* dst = reinterpret_cast<float4*>(
          &lds[(c*CHS + cs)*68 + orow*8 + 4*cp]);
      *dst = make_float4(a0*(1.0f/9.0f), a1*(1.0f/9.0f),
                         a2*(1.0f/9.0f), a3*(1.0f/9.0f));
    }
  }
  __syncthreads();                    // all tiles staged; RAW dead

  // ---- sample's 8x8 tile into registers ----
  float xd[64];
  #pragma unroll
  for (int r = 0; r < 8; r++) {
    const float4* src = reinterpret_cast<const float4*>(&lds[t*68 + r*8]);
    float4 a = src[0], bq = src[1];
    xd[r*8+0]=a.x;  xd[r*8+1]=a.y;  xd[r*8+2]=a.z;  xd[r*8+3]=a.w;
    xd[r*8+4]=bq.x; xd[r*8+5]=bq.y; xd[r*8+6]=bq.z; xd[r*8+7]=bq.w;
  }

  // ---- stage 1 (R0 structure; weights via scalar loads) ----
  float logits[10];
  #pragma unroll
  for (int c = 0; c < 10; c++) logits[c] = fcb1[c];

  #pragma unroll 1
  for (int ch = 0; ch < 20; ch++) {
    float w[9];
    #pragma unroll
    for (int k = 0; k < 9; k++) w[k] = W1F[ch*9 + k];     // uniform -> s_load
    float bb = B1F[ch];
    float feat[9];
    #pragma unroll
    for (int pr = 0; pr < 3; pr++) {
      #pragma unroll
      for (int pc = 0; pc < 3; pc++) {
        float c00 = bb, c01 = bb, c10 = bb, c11 = bb;
        #pragma unroll
        for (int dr = 0; dr < 3; dr++) {
          #pragma unroll
          for (int dc = 0; dc < 3; dc++) {
            float wk = w[dr*3 + dc];
            c00 = fmaf(xd[(2*pr+0+dr)*8 + 2*pc+0+dc], wk, c00);
            c01 = fmaf(xd[(2*pr+0+dr)*8 + 2*pc+1+dc], wk, c01);
            c10 = fmaf(xd[(2*pr+1+dr)*8 + 2*pc+0+dc], wk, c10);
            c11 = fmaf(xd[(2*pr+1+dr)*8 + 2*pc+1+dc], wk, c11);
          }
        }
        feat[pr*3+pc] = fmaxf(fmaxf(fmaxf(c00, c01), fmaxf(c10, c11)), 0.0f);
      }
    }
    #pragma unroll
    for (int c = 0; c < 10; c++) {
      float acc = logits[c];
      #pragma unroll
      for (int p = 0; p < 9; p++)
        acc = fmaf(feat[p], fcw1[c*180 + ch*9 + p], acc);  // uniform -> s_load
      logits[c] = acc;
    }
  }

  // ---- top-2 (stable-argsort tie semantics: later index wins on tie) ----
  int i1 = 0; float v1m = logits[0];
  #pragma unroll
  for (int c = 1; c < 10; c++) { if (logits[c] >= v1m) { v1m = logits[c]; i1 = c; } }
  int i2 = 0; float v2m = -3.0e38f;
  #pragma unroll
  for (int c = 0; c < 10; c++) { if (c != i1 && logits[c] >= v2m) { v2m = logits[c]; i2 = c; } }
  const int idx0 = i1 < i2 ? i1 : i2;
  const int idx1 = i1 < i2 ? i2 : i1;
  int eid = 8*idx0 - (idx0*(idx0-1))/2 + idx1 - 1;   // PAIR_TABLE[idx0][idx1]
  eid = eid < 0 ? 0 : (eid > 44 ? 44 : eid);          // guard garbage lanes

  float mx = v1m;
  float sume = 0.0f;
  #pragma unroll
  for (int c = 0; c < 10; c++) sume += expf(logits[c] - mx);
  const bool use1 = (-logf(sume)) > 0.3f;

  // ---- stage 2 (R0 structure + prefetch; bias/fcb2 packed in W2F) ----
  const float4* W2F4 = reinterpret_cast<const float4*>(ws);
  const float4* FC24 = reinterpret_cast<const float4*>(ws + OFF_FC2);

  float4 wv[7], fa, fb;
  #pragma unroll
  for (int k4 = 0; k4 < 7; k4++) wv[k4] = W2F4[k4*45 + eid];
  fa = FC24[eid];
  fb = FC24[15*45 + eid];

  float s2a = wv[6].z;               // fcb2[e][0]  (slot 26, o==0)
  float s2b = wv[6].w;               // fcb2[e][1]  (slot 27, o==0)

  #pragma unroll 1
  for (int o = 0; o < 15; o++) {
    float4 nwv[7], nfa, nfb;
    if (o < 14) {                    // prefetch next channel's tables
      #pragma unroll
      for (int k4 = 0; k4 < 7; k4++) nwv[k4] = W2F4[((o+1)*7 + k4)*45 + eid];
      nfa = FC24[(o+1)*45 + eid];
      nfb = FC24[(15 + o+1)*45 + eid];
    }
    const float bias = wv[6].y;      // folded bias (slot 25)
    float feat0 = 0.f, feat1 = 0.f, feat2 = 0.f, feat3 = 0.f;
    #pragma unroll
    for (int ph = 0; ph < 2; ph++) {
      #pragma unroll
      for (int pw = 0; pw < 2; pw++) {
        float c00 = bias, c01 = bias, c10 = bias, c11 = bias;
        #pragma unroll
        for (int i = 0; i < 5; i++) {
          #pragma unroll
          for (int j = 0; j < 5; j++) {
            float wk = GETC(wv, i*5 + j);
            c00 = fmaf(xd[(2*ph+0+i)*8 + 2*pw+0+j], wk, c00);
            c01 = fmaf(xd[(2*ph+0+i)*8 + 2*pw+1+j], wk, c01);
            c10 = fmaf(xd[(2*ph+1+i)*8 + 2*pw+0+j], wk, c10);
            c11 = fmaf(xd[(2*ph+1+i)*8 + 2*pw+1+j], wk, c11);
          }
        }
        float f = fmaxf(fmaxf(fmaxf(c00, c01), fmaxf(c10, c11)), 0.0f);
        if (ph == 0 && pw == 0) feat0 = f;
        else if (ph == 0)       feat1 = f;
        else if (pw == 0)       feat2 = f;
        else                    feat3 = f;
      }
    }
    s2a = fmaf(feat0, fa.x, fmaf(feat1, fa.y, fmaf(feat2, fa.z, fmaf(feat3, fa.w, s2a))));
    s2b = fmaf(feat0, fb.x, fmaf(feat1, fb.y, fmaf(feat2, fb.z, fmaf(feat3, fb.w, s2b))));
    if (o < 14) {
      #pragma unroll
      for (int k4 = 0; k4 < 7; k4++) wv[k4] = nwv[k4];
      fa = nfa; fb = nfb;
    }
  }

  // ---- scatter + log_softmax (R0 structure) ----
  float o10[10];
  #pragma unroll
  for (int c = 0; c < 10; c++) {
    float v = -100.0f;
    v = (c == idx0) ? s2a : v;
    v = (c == idx1) ? s2b : v;
    o10[c] = use1 ? logits[c] : v;
  }
  float m2x = o10[0];
  #pragma unroll
  for (int c = 1; c < 10; c++) m2x = fmaxf(m2x, o10[c]);
  float se2 = 0.0f;
  #pragma unroll
  for (int c = 0; c < 10; c++) se2 += expf(o10[c] - m2x);
  const float lse2 = m2x + logf(se2);

  // ---- stage outputs in dead RAW region; coalesced float4 stores ----
  #pragma unroll
  for (int c = 0; c < 10; c++) lds[T_RAW + t*10 + c] = logits[c];
  #pragma unroll
  for (int c = 0; c < 10; c++) lds[T_RAW + 1280 + t*10 + c] = o10[c] - lse2;
  __syncthreads();

  if (B0 + NS <= B) {                // full block: coalesced path
    const float4* l4 = reinterpret_cast<const float4*>(&lds[T_RAW]);
    float4* o1 = reinterpret_cast<float4*>(out + (size_t)B0*10);
    float4* o2 = reinterpret_cast<float4*>(out + (size_t)B*10 + (size_t)B0*10);
    #pragma unroll
    for (int k = 0; k < 3; k++) {
      const int f = t + 128*k;
      if (f < 320) { o1[f] = l4[f]; o2[f] = l4[320 + f]; }
    }
  } else if (B0 + t < B) {           // tail block fallback
    const size_t base = (size_t)(B0 + t)*10;
    #pragma unroll
    for (int c = 0; c < 10; c++) out[base + c] = lds[T_RAW + t*10 + c];
    #pragma unroll
    for (int c = 0; c < 10; c++) out[(size_t)B*10 + base + c] = lds[T_RAW + 1280 + t*10 + c];
  }
}

extern "C" void kernel_launch(void* const* d_in, const int* in_sizes, int n_in,
                              void* d_out, int out_size, void* d_ws, size_t ws_size,
                              hipStream_t stream) {
  const float* x    = (const float*)d_in[0];
  const float* w1   = (const float*)d_in[1];
  const float* b1   = (const float*)d_in[2];
  const float* g1   = (const float*)d_in[3];
  const float* be1  = (const float*)d_in[4];
  const float* m1   = (const float*)d_in[5];
  const float* v1   = (const float*)d_in[6];
  const float* fcw1 = (const float*)d_in[7];
  const float* fcb1 = (const float*)d_in[8];
  const float* w2   = (const float*)d_in[9];
  const float* b2   = (const float*)d_in[10];
  const float* g2   = (const float*)d_in[11];
  const float* be2  = (const float*)d_in[12];
  const float* m2   = (const float*)d_in[13];
  const float* v2   = (const float*)d_in[14];
  const float* fcw2 = (const float*)d_in[15];
  const float* fcb2 = (const float*)d_in[16];
  float* out = (float*)d_out;
  float* ws  = (float*)d_ws;
  const int B = in_sizes[0] / 784;

  setup_tables<<<80, 256, 0, stream>>>(w1, b1, g1, be1, m1, v1,
                                       w2, b2, g2, be2, m2, v2, fcw2, fcb2, ws);
  fused_k<<<(B + NS - 1)/NS, 128, 0, stream>>>(x, ws, fcw1, fcb1, out, B);
}

// Round 8
// 358.751 us; speedup vs baseline: 1.0601x; 1.0601x over previous
//
#include <hip/hip_runtime.h>
#include <cmath>

#define EPSF 1e-5f

// ---------------------------------------------------------------------------
// ws float layout:
//   W2F   = ws      : float4[15][7][45] folded stage-2 conv weights, expert
//                     innermost.  k=25 -> folded bias; k=26/27 -> fcb2[e][0/1]
//                     for o==0 (zero elsewhere).
//   FC2P  = +18900  : float[2][15][4][45] fcw2 component-major (pos, expert inner)
//   FCW1R = +24300  : float[20][9][12] fcw1 re-laid [ch][pp][class pad 10->12]
//   W1F   = +26460  : float[20][9]  folded stage-1 conv weights
//   B1F   = +26640  : float[20]     folded stage-1 bias
// total 26660 floats (~107 KB)
// ---------------------------------------------------------------------------
#define OFF_FC2P  18900
#define OFF_FCW1R 24300
#define OFF_W1F   26460
#define OFF_B1F   26640

__global__ __launch_bounds__(256) void setup_tables(
    const float* __restrict__ w1, const float* __restrict__ b1,
    const float* __restrict__ g1, const float* __restrict__ be1,
    const float* __restrict__ m1, const float* __restrict__ v1,
    const float* __restrict__ w2, const float* __restrict__ b2,
    const float* __restrict__ g2, const float* __restrict__ be2,
    const float* __restrict__ m2, const float* __restrict__ v2,
    const float* __restrict__ fcw2, const float* __restrict__ fcb2,
    const float* __restrict__ fcw1,
    float* __restrict__ ws)
{
  const int t  = blockIdx.x * blockDim.x + threadIdx.x;
  const int nt = gridDim.x * blockDim.x;
  float* W2F   = ws;
  float* FC2P  = ws + OFF_FC2P;
  float* FCW1R = ws + OFF_FCW1R;
  float* W1F   = ws + OFF_W1F;
  float* B1F   = ws + OFF_B1F;

  for (int idx = t; idx < 18900; idx += nt) {
    int kk = idx & 3, rest = idx >> 2;
    int e = rest % 45, ok4 = rest / 45;
    int k4 = ok4 % 7, o = ok4 / 7;
    int k = k4 * 4 + kk;
    float s = g2[e*15+o] / sqrtf(v2[e*15+o] + EPSF);
    float v;
    if (k < 25)       v = w2[(e*15+o)*25 + k] * s;
    else if (k == 25) v = b2[e*15+o]*s + be2[e*15+o] - m2[e*15+o]*s;
    else if (k == 26) v = (o == 0) ? fcb2[e*2 + 0] : 0.0f;
    else              v = (o == 0) ? fcb2[e*2 + 1] : 0.0f;
    W2F[idx] = v;
  }
  // FC2P[((oo*15+o)*4+pos)*45 + e] = fcw2[(e*2+oo)*60 + o*4 + pos]
  for (int idx = t; idx < 5400; idx += nt) {
    int e = idx % 45, r = idx / 45;
    int pos = r % 4, r2 = r / 4;
    int o = r2 % 15, oo = r2 / 15;
    FC2P[idx] = fcw2[(e*2+oo)*60 + o*4 + pos];
  }
  for (int idx = t; idx < 2160; idx += nt) {
    int c = idx % 12, r2 = idx / 12, pp = r2 % 9, ch = r2 / 9;
    FCW1R[idx] = (c < 10) ? fcw1[c*180 + ch*9 + pp] : 0.0f;
  }
  for (int idx = t; idx < 180; idx += nt) {
    int ch = idx / 9;
    float s = g1[ch] / sqrtf(v1[ch] + EPSF);
    W1F[idx] = w1[idx] * s;
  }
  for (int idx = t; idx < 20; idx += nt) {
    float s = g1[idx] / sqrtf(v1[idx] + EPSF);
    B1F[idx] = b1[idx]*s + be1[idx] - m1[idx]*s;
  }
}

#define GETC(arr, k) ((k)%4==0 ? arr[(k)/4].x : (k)%4==1 ? arr[(k)/4].y : \
                      (k)%4==2 ? arr[(k)/4].z : arr[(k)/4].w)

// ---------------------------------------------------------------------------
// 4 threads per sample, spatial split (R5 skeleton: passed, spill-free, 16
// waves/CU).  R5's measured tax: ~240 ds_read_b128/wave of fc table reads =
// 19-30 us/CU of LDS-pipe serialization.  Fix: ALL stage-1 tables come
// through the SCALAR pipe --
//   * fc1: iterate global pp 0..8.  Row (ch*9+pp) is lane-uniform -> s_load;
//     each lane contributes its owned feat (compile-time (q,lp) ownership
//     table) or 0.
//   * W1F/B1F/fcb1: lane-uniform -> s_load.
//   * stage-2 biases packed into W2F k=25 (folded bias) and k=26/27 (fcb2,
//     nonzero only at o==0; added once via part-0-gated init).
// STAGE-2 BUG FIX vs R7: loop ALL 15 channels per part (part p contributes
// feat[o][pos=p] * fc[o][pos=p] for every o; butterfly over parts restores
// the full 60-term sum).  R7's o=p+4*oi variant computed only 15/60 terms.
// LDS is staging-only.  LDS (floats) 9760 = 39 KB -> 4 blocks/CU = 16 w/CU:
//   [0,4352)    xds: 64 samples x 68-stride; reused: [0,640) out1 [640,1280) out2
//   [4352,9760) RAW: 8-sample chunk staging (stride 676)
// ---------------------------------------------------------------------------
#define T_RAW   4352
#define SSTR    676

__global__ __launch_bounds__(256) void fused_k(
    const float* __restrict__ x,
    const float* __restrict__ ws,
    const float* __restrict__ fcb1,
    float* __restrict__ out, int B)
{
  __shared__ float lds[9760];

  const int t  = threadIdx.x;
  const int p  = t & 3;            // part / quadrant 0..3
  const int sl = t >> 2;           // sample slot 0..63
  const int b  = blockIdx.x * 64 + sl;
  const bool valid = (b < B);

  const float* FC2P  = ws + OFF_FC2P;
  const float* FCW1R = ws + OFF_FCW1R;
  const float* W1F   = ws + OFF_W1F;
  const float* B1F   = ws + OFF_B1F;

  // ---- staging thread mapping ----
  const int s8  = t >> 5;          // sample-in-chunk 0..7
  const int tin = t & 31;          // loads float4 tin+32j

  // ---- prologue: load chunk 0 (rows 0..23, 168 float4/sample, coalesced) ----
  float4 pre[6];
  {
    const int bs = blockIdx.x * 64 + s8;
    if (bs < B) {
      const float4* xp = reinterpret_cast<const float4*>(x + (size_t)bs * 784);
      #pragma unroll
      for (int j = 0; j < 5; j++) pre[j] = xp[tin + 32*j];
      pre[5] = (tin < 8) ? xp[tin + 160] : make_float4(0.f,0.f,0.f,0.f);
    } else {
      #pragma unroll
      for (int j = 0; j < 6; j++) pre[j] = make_float4(0.f,0.f,0.f,0.f);
    }
    float4* rw = reinterpret_cast<float4*>(&lds[T_RAW + s8*SSTR]);
    #pragma unroll
    for (int j = 0; j < 5; j++) rw[tin + 32*j] = pre[j];
    if (tin < 8) rw[tin + 160] = pre[5];
  }
  __syncthreads();

  // ---- 8 chunks: prefetch c+1 || downscale c ----
  #pragma unroll 1
  for (int c = 0; c < 8; c++) {
    if (c < 7) {
      const int bs = blockIdx.x * 64 + (c+1)*8 + s8;
      if (bs < B) {
        const float4* xp = reinterpret_cast<const float4*>(x + (size_t)bs * 784);
        #pragma unroll
        for (int j = 0; j < 5; j++) pre[j] = xp[tin + 32*j];
        pre[5] = (tin < 8) ? xp[tin + 160] : make_float4(0.f,0.f,0.f,0.f);
      }
    }
    if (t < 128) {
      const int ds8  = t >> 4;
      const int orow = (t >> 1) & 7;
      const int h    = t & 1;
      float a0 = 0.f, a1 = 0.f, a2 = 0.f, a3 = 0.f;
      #pragma unroll
      for (int dr = 0; dr < 3; dr++) {
        const float4* rp = reinterpret_cast<const float4*>(
            &lds[T_RAW + ds8*SSTR + (3*orow + dr)*28 + 12*h]);
        float4 q0 = rp[0], q1 = rp[1], q2 = rp[2];
        a0 += q0.x + q0.y + q0.z;
        a1 += q0.w + q1.x + q1.y;
        a2 += q1.z + q1.w + q2.x;
        a3 += q2.y + q2.z + q2.w;
      }
      float4* dst = reinterpret_cast<float4*>(&lds[(c*8 + ds8)*68 + orow*8 + 4*h]);
      *dst = make_float4(a0*(1.f/9.f), a1*(1.f/9.f), a2*(1.f/9.f), a3*(1.f/9.f));
    }
    __syncthreads();                   // raw(c) reads done; xds(c) visible
    if (c < 7) {
      float4* rw = reinterpret_cast<float4*>(&lds[T_RAW + s8*SSTR]);
      #pragma unroll
      for (int j = 0; j < 5; j++) rw[tin + 32*j] = pre[j];
      if (tin < 8) rw[tin + 160] = pre[5];
      __syncthreads();                 // raw(c+1) visible
    }
  }

  // ---- part's 6x6 quadrant into registers ----
  const int R0 = p & 2;
  const int C0 = (p & 1) * 2;
  float xl[36];
  #pragma unroll
  for (int lr = 0; lr < 6; lr++) {
    const float2* src = reinterpret_cast<const float2*>(&lds[sl*68 + (R0+lr)*8 + C0]);
    float2 q0 = src[0], q1 = src[1], q2 = src[2];
    xl[lr*6+0]=q0.x; xl[lr*6+1]=q0.y; xl[lr*6+2]=q1.x;
    xl[lr*6+3]=q1.y; xl[lr*6+4]=q2.x; xl[lr*6+5]=q2.y;
  }

  // ---- stage 1: conv (4 local pool positions), fc via s_load rows ----
  float logits[10];
  #pragma unroll
  for (int c = 0; c < 10; c++) logits[c] = 0.0f;

  #pragma unroll 1
  for (int ch = 0; ch < 20; ch++) {
    float w_[9];
    #pragma unroll
    for (int k = 0; k < 9; k++) w_[k] = W1F[ch*9 + k];     // uniform -> s_load
    const float bb = B1F[ch];                               // uniform -> s_load
    float feat[4];
    #pragma unroll
    for (int lp = 0; lp < 4; lp++) {
      const int lpr = lp >> 1, lpc = lp & 1;
      float c00 = bb, c01 = bb, c10 = bb, c11 = bb;
      #pragma unroll
      for (int dr = 0; dr < 3; dr++) {
        #pragma unroll
        for (int dc = 0; dc < 3; dc++) {
          const float wk = w_[dr*3 + dc];
          c00 = fmaf(xl[(2*lpr+0+dr)*6 + 2*lpc+0+dc], wk, c00);
          c01 = fmaf(xl[(2*lpr+0+dr)*6 + 2*lpc+1+dc], wk, c01);
          c10 = fmaf(xl[(2*lpr+1+dr)*6 + 2*lpc+0+dc], wk, c10);
          c11 = fmaf(xl[(2*lpr+1+dr)*6 + 2*lpc+1+dc], wk, c11);
        }
      }
      feat[lp] = fmaxf(fmaxf(fmaxf(c00, c01), fmaxf(c10, c11)), 0.0f);
    }
    // fc over global pool positions; row address wave-uniform -> s_load.
    // pp -> (owner quadrant, local lp):
    //   p0 covers pp{0,1,3,4} owns {0,3}; p1 covers {1,2,4,5} owns {1,2};
    //   p2 covers {3,4,6,7} owns {4,6,7}; p3 covers {4,5,7,8} owns {5,8}.
    const int QOWN[9]  = {0,1,1,0,2,3,2,2,3};
    const int LPOWN[9] = {0,0,1,2,1,1,2,3,3};
    #pragma unroll
    for (int pp = 0; pp < 9; pp++) {
      const float* R = FCW1R + (ch*9 + pp)*12;             // uniform -> s_load
      const float fm = (p == QOWN[pp]) ? feat[LPOWN[pp]] : 0.0f;
      #pragma unroll
      for (int c = 0; c < 10; c++) logits[c] = fmaf(fm, R[c], logits[c]);
    }
  }

  // butterfly all-reduce over the 4 parts, + bias (uniform s_load)
  #pragma unroll
  for (int c = 0; c < 10; c++) {
    float v = logits[c];
    v += __shfl_xor(v, 1);
    v += __shfl_xor(v, 2);
    logits[c] = v + fcb1[c];
  }

  // ---- top-2 (stable-argsort tie semantics) ----
  int i1 = 0; float v1m = logits[0];
  #pragma unroll
  for (int c = 1; c < 10; c++) { if (logits[c] >= v1m) { v1m = logits[c]; i1 = c; } }
  int i2 = 0; float v2m = -3.0e38f;
  #pragma unroll
  for (int c = 0; c < 10; c++) { if (c != i1 && logits[c] >= v2m) { v2m = logits[c]; i2 = c; } }
  const int idx0 = i1 < i2 ? i1 : i2;
  const int idx1 = i1 < i2 ? i2 : i1;
  int eid = 8*idx0 - (idx0*(idx0-1))/2 + idx1 - 1;
  eid = eid < 0 ? 0 : (eid > 44 ? 44 : eid);

  float sume = 0.0f;
  #pragma unroll
  for (int c = 0; c < 10; c++) sume += __expf(logits[c] - v1m);
  const bool use1 = (-__logf(sume)) > 0.3f;

  // ---- stash logits (= out1) in LDS; frees them across stage 2 ----
  __syncthreads();                       // all reads of xds region done
  if (p == 0) {
    #pragma unroll
    for (int c = 0; c < 5; c++) lds[sl*10 + c] = logits[c];
  } else if (p == 1) {
    #pragma unroll
    for (int c = 5; c < 10; c++) lds[sl*10 + c] = logits[c];
  }

  // ---- stage 2: ALL 15 channels at this part's pool position p ----
  const float4* W2F4 = reinterpret_cast<const float4*>(ws);

  // fcb2 (packed in o==0 slots 26/27) added once: part-0-gated init.
  const float4 wb = W2F4[6*45 + eid];          // o=0, k4=6
  float s2a = (p == 0) ? wb.z : 0.0f;
  float s2b = (p == 0) ? wb.w : 0.0f;

  #pragma unroll 1
  for (int o = 0; o < 15; o++) {
    const float4 wv6 = W2F4[(o*7 + 6)*45 + eid];   // k=24, bias(k=25)
    const float fa = FC2P[(o*4 + p)*45 + eid];
    const float fb = FC2P[((15 + o)*4 + p)*45 + eid];
    const float bias = wv6.y;
    float c00 = bias, c01 = bias, c10 = bias, c11 = bias;
    #pragma unroll
    for (int g = 0; g < 6; g++) {                  // stream wv: <=2 live
      const float4 wg = W2F4[(o*7 + g)*45 + eid];
      #pragma unroll
      for (int kk = 0; kk < 4; kk++) {
        const int k = 4*g + kk;
        const int i = k / 5, j = k % 5;
        const float wk = (kk==0) ? wg.x : (kk==1) ? wg.y : (kk==2) ? wg.z : wg.w;
        c00 = fmaf(xl[(0+i)*6 + 0+j], wk, c00);
        c01 = fmaf(xl[(0+i)*6 + 1+j], wk, c01);
        c10 = fmaf(xl[(1+i)*6 + 0+j], wk, c10);
        c11 = fmaf(xl[(1+i)*6 + 1+j], wk, c11);
      }
    }
    {                                              // k = 24 (i=4, j=4)
      const float wk = wv6.x;
      c00 = fmaf(xl[4*6 + 4], wk, c00);
      c01 = fmaf(xl[4*6 + 5], wk, c01);
      c10 = fmaf(xl[5*6 + 4], wk, c10);
      c11 = fmaf(xl[5*6 + 5], wk, c11);
    }
    const float f = fmaxf(fmaxf(fmaxf(c00, c01), fmaxf(c10, c11)), 0.0f);
    s2a = fmaf(f, fa, s2a);
    s2b = fmaf(f, fb, s2b);
  }
  s2a += __shfl_xor(s2a, 1); s2a += __shfl_xor(s2a, 2);
  s2b += __shfl_xor(s2b, 1); s2b += __shfl_xor(s2b, 2);

  // ---- scatter + log_softmax (logits from LDS) ----
  __syncthreads();
  float o10[10];
  #pragma unroll
  for (int c = 0; c < 10; c++) {
    float v = -100.0f;
    v = (c == idx0) ? s2a : v;
    v = (c == idx1) ? s2b : v;
    o10[c] = use1 ? lds[sl*10 + c] : v;
  }
  float m2x = o10[0];
  #pragma unroll
  for (int c = 1; c < 10; c++) m2x = fmaxf(m2x, o10[c]);
  float se2 = 0.0f;
  #pragma unroll
  for (int c = 0; c < 10; c++) se2 += __expf(o10[c] - m2x);
  const float lse2 = m2x + __logf(se2);

  // ---- stage out2 into LDS; coalesced float4 block store ----
  if (p == 2) {
    #pragma unroll
    for (int c = 0; c < 5; c++) lds[640 + sl*10 + c] = o10[c] - lse2;
  } else if (p == 3) {
    #pragma unroll
    for (int c = 5; c < 10; c++) lds[640 + sl*10 + c] = o10[c] - lse2;
  }
  __syncthreads();

  if (blockIdx.x * 64 + 64 <= B) {
    const float4* l4 = reinterpret_cast<const float4*>(lds);
    const size_t o1 = (size_t)blockIdx.x * 640;
    if (t < 160)
      *reinterpret_cast<float4*>(out + o1 + (size_t)t*4) = l4[t];
    if (t >= 96)
      *reinterpret_cast<float4*>(out + (size_t)B*10 + o1 + (size_t)(t-96)*4) = l4[160 + (t-96)];
  } else if (valid) {
    const size_t base = (size_t)b * 10;
    if (p == 0) {
      #pragma unroll
      for (int c = 0; c < 5; c++) out[base + c] = lds[sl*10 + c];
    } else if (p == 1) {
      #pragma unroll
      for (int c = 5; c < 10; c++) out[base + c] = lds[sl*10 + c];
    } else if (p == 2) {
      #pragma unroll
      for (int c = 0; c < 5; c++) out[(size_t)B*10 + base + c] = lds[640 + sl*10 + c];
    } else {
      #pragma unroll
      for (int c = 5; c < 10; c++) out[(size_t)B*10 + base + c] = lds[640 + sl*10 + c];
    }
  }
}

extern "C" void kernel_launch(void* const* d_in, const int* in_sizes, int n_in,
                              void* d_out, int out_size, void* d_ws, size_t ws_size,
                              hipStream_t stream) {
  const float* x    = (const float*)d_in[0];
  const float* w1   = (const float*)d_in[1];
  const float* b1   = (const float*)d_in[2];
  const float* g1   = (const float*)d_in[3];
  const float* be1  = (const float*)d_in[4];
  const float* m1   = (const float*)d_in[5];
  const float* v1   = (const float*)d_in[6];
  const float* fcw1 = (const float*)d_in[7];
  const float* fcb1 = (const float*)d_in[8];
  const float* w2   = (const float*)d_in[9];
  const float* b2   = (const float*)d_in[10];
  const float* g2   = (const float*)d_in[11];
  const float* be2  = (const float*)d_in[12];
  const float* m2   = (const float*)d_in[13];
  const float* v2   = (const float*)d_in[14];
  const float* fcw2 = (const float*)d_in[15];
  const float* fcb2 = (const float*)d_in[16];
  float* out = (float*)d_out;
  float* ws  = (float*)d_ws;
  const int B = in_sizes[0] / 784;

  setup_tables<<<80, 256, 0, stream>>>(w1, b1, g1, be1, m1, v1,
                                       w2, b2, g2, be2, m2, v2,
                                       fcw2, fcb2, fcw1, ws);
  fused_k<<<(B + 63)/64, 256, 0, stream>>>(x, ws, fcb1, out, B);
}

// Round 9
// 346.625 us; speedup vs baseline: 1.0972x; 1.0350x over previous
//
#include <hip/hip_runtime.h>
#include <cmath>

#define EPSF 1e-5f

// ---------------------------------------------------------------------------
// ws float layout:
//   W2F = ws      : float4[15][7][45] folded stage-2 conv weights, expert
//                   innermost.  k=25 -> folded BN bias; k=26/27 -> fcb2[e][0/1]
//                   packed at o==0 (zero elsewhere -> adding per-o is exact).
//   FC2 = +18900  : float4[2][15][45] fcw2 re-laid (expert innermost)
//   IMG = +24300  : float [2432] table image (copied to LDS TAB by fused_k):
//       [0,240)     W1P   [20][12] folded stage-1 conv w (row pad 9->12)
//       [240,2400)  FCW1R [20][9][12] fcw1 re-laid [ch][pp][class pad 10->12]
//       [2400,2420) B1F   [20] folded stage-1 bias
//       [2420,2432) FCB1  [10] (+2 pad)
// total 26732 floats (~107 KB)
// ---------------------------------------------------------------------------
#define OFF_FC2 18900
#define OFF_IMG 24300

#define I_W1P   0
#define I_FCW1R 240
#define I_B1F   2400
#define I_FCB1  2420
#define IMG_SZ  2432

__global__ __launch_bounds__(256) void setup_tables(
    const float* __restrict__ w1, const float* __restrict__ b1,
    const float* __restrict__ g1, const float* __restrict__ be1,
    const float* __restrict__ m1, const float* __restrict__ v1,
    const float* __restrict__ w2, const float* __restrict__ b2,
    const float* __restrict__ g2, const float* __restrict__ be2,
    const float* __restrict__ m2, const float* __restrict__ v2,
    const float* __restrict__ fcw2, const float* __restrict__ fcb2,
    const float* __restrict__ fcw1, const float* __restrict__ fcb1,
    float* __restrict__ ws)
{
  const int t  = blockIdx.x * blockDim.x + threadIdx.x;
  const int nt = gridDim.x * blockDim.x;
  float* W2F = ws;
  float* FC2 = ws + OFF_FC2;
  float* IMG = ws + OFF_IMG;

  for (int idx = t; idx < 18900; idx += nt) {
    int kk = idx & 3, rest = idx >> 2;
    int e = rest % 45, ok4 = rest / 45;
    int k4 = ok4 % 7, o = ok4 / 7;
    int k = k4 * 4 + kk;
    float s = g2[e*15+o] / sqrtf(v2[e*15+o] + EPSF);
    float v;
    if (k < 25)       v = w2[(e*15+o)*25 + k] * s;
    else if (k == 25) v = b2[e*15+o]*s + be2[e*15+o] - m2[e*15+o]*s;
    else if (k == 26) v = (o == 0) ? fcb2[e*2 + 0] : 0.0f;
    else              v = (o == 0) ? fcb2[e*2 + 1] : 0.0f;
    W2F[idx] = v;
  }
  for (int idx = t; idx < 5400; idx += nt) {
    int kk = idx & 3, rest = idx >> 2;
    int e = rest % 45, t2 = rest / 45;
    int f4 = t2 % 15, oo = t2 / 15;
    FC2[idx] = fcw2[(e*2+oo)*60 + f4*4 + kk];
  }
  for (int i = t; i < IMG_SZ; i += nt) {
    float v = 0.0f;
    if (i < I_FCW1R) {                       // W1P
      int ch = i / 12, j = i % 12;
      if (j < 9) {
        float s = g1[ch] / sqrtf(v1[ch] + EPSF);
        v = w1[ch*9 + j] * s;
      }
    } else if (i < I_B1F) {                  // FCW1R
      int k = i - I_FCW1R;
      int c = k % 12, r2 = k / 12, pp = r2 % 9, ch = r2 / 9;
      if (c < 10) v = fcw1[c*180 + ch*9 + pp];
    } else if (i < I_FCB1) {                 // B1F
      int ch = i - I_B1F;
      float s = g1[ch] / sqrtf(v1[ch] + EPSF);
      v = b1[ch]*s + be1[ch] - m1[ch]*s;
    } else {                                 // FCB1
      int k = i - I_FCB1;
      if (k < 10) v = fcb1[k];
    }
    IMG[i] = v;
  }
}

#define GETC(arr, k) ((k)%4==0 ? arr[(k)/4].x : (k)%4==1 ? arr[(k)/4].y : \
                      (k)%4==2 ? arr[(k)/4].z : arr[(k)/4].w)

// ---------------------------------------------------------------------------
// 4 threads per sample, CHANNEL split (the R2-config, best measured ~96 us):
//   stage 1: part p owns channels p*5..p*5+4 -- full 3x3 pool grid per
//            channel, fc rows from LDS TAB.  ZERO FMA waste (vs spatial's
//            1.8x conv + 4x fc).  fc row address depends only on p -> 4
//            distinct LDS addresses/wave, 16-way broadcast, ~conflict-free.
//   stage 2: part p owns channels {p, p+4, p+8, p+12} (p=3: 3), full 2x2
//            pool; bias/fcb2 from W2F slots 25/26/27 (R8-proven; slots 26/27
//            are exact zeros for o!=0 so per-o add is exact).
//   butterfly xor1+xor2 all-reduces logits / s2 (bit-identical on 4 lanes).
// 128-THREAD BLOCKS (R6-proven): allocator grants ~132 VGPR -> xd[64] lives
// in registers, no spill (R1: 256-thr got 84 and spilled; R3: 64 and remat).
// LDS 7312 floats = 29.2 KB -> 5 blocks/CU = 10 waves/CU:
//   [0,2176)     xds: 32 samples x 68-stride (8x8 tile at sl*68)
//                -- reused after stage 1: [0,320) out1, [320,640) out2
//   [2176,4880)  RAW: 4-sample chunk staging (stride 676)
//   [4880,7312)  TAB: table image (W1P/FCW1R/B1F/FCB1)
// ---------------------------------------------------------------------------
#define T_RAW 2176
#define T_TAB 4880
#define SSTR  676

__global__ __launch_bounds__(128, 1) void fused_k(
    const float* __restrict__ x,
    const float* __restrict__ ws,
    float* __restrict__ out, int B)
{
  __shared__ float lds[7312];

  const int t  = threadIdx.x;
  const int p  = t & 3;            // part 0..3
  const int sl = t >> 2;           // sample slot 0..31
  const int b  = blockIdx.x * 32 + sl;
  const bool valid = (b < B);

  // ---- TAB copy: issue L2 loads first, store to LDS (transient regs) ----
  {
    const float4* img4 = reinterpret_cast<const float4*>(ws + OFF_IMG);
    float4* tab4 = reinterpret_cast<float4*>(&lds[T_TAB]);
    #pragma unroll
    for (int k = 0; k < 5; k++) {
      const int i = t + 128*k;
      if (i < IMG_SZ/4) tab4[i] = img4[i];
    }
  }

  // ---- staging mapping: 4-sample chunks, 32 threads/sample ----
  const int s4  = t >> 5;          // sample-in-chunk 0..3
  const int tin = t & 31;          // loads float4 tin+32j

  // ---- prologue: load chunk 0 (rows 0..23, 168 float4/sample, coalesced) ----
  float4 pre[6];
  {
    const int bs = blockIdx.x * 32 + s4;
    if (bs < B) {
      const float4* xp = reinterpret_cast<const float4*>(x + (size_t)bs * 784);
      #pragma unroll
      for (int j = 0; j < 5; j++) pre[j] = xp[tin + 32*j];
      pre[5] = (tin < 8) ? xp[tin + 160] : make_float4(0.f,0.f,0.f,0.f);
    } else {
      #pragma unroll
      for (int j = 0; j < 6; j++) pre[j] = make_float4(0.f,0.f,0.f,0.f);
    }
    float4* rw = reinterpret_cast<float4*>(&lds[T_RAW + s4*SSTR]);
    #pragma unroll
    for (int j = 0; j < 5; j++) rw[tin + 32*j] = pre[j];
    if (tin < 8) rw[tin + 160] = pre[5];
  }
  __syncthreads();

  // ---- 8 chunks: prefetch c+1 || downscale c ----
  #pragma unroll 1
  for (int c = 0; c < 8; c++) {
    if (c < 7) {                       // issue next chunk's loads early
      const int bs = blockIdx.x * 32 + (c+1)*4 + s4;
      if (bs < B) {
        const float4* xp = reinterpret_cast<const float4*>(x + (size_t)bs * 784);
        #pragma unroll
        for (int j = 0; j < 5; j++) pre[j] = xp[tin + 32*j];
        pre[5] = (tin < 8) ? xp[tin + 160] : make_float4(0.f,0.f,0.f,0.f);
      }
    }
    // downscale chunk c: thread (ds4, orow, h) -> tile[orow][4h..4h+3]
    if (t < 64) {
      const int ds4  = t >> 4;
      const int orow = (t >> 1) & 7;
      const int h    = t & 1;
      float a0 = 0.f, a1 = 0.f, a2 = 0.f, a3 = 0.f;
      #pragma unroll
      for (int dr = 0; dr < 3; dr++) {
        const float4* rp = reinterpret_cast<const float4*>(
            &lds[T_RAW + ds4*SSTR + (3*orow + dr)*28 + 12*h]);
        float4 q0 = rp[0], q1 = rp[1], q2 = rp[2];
        a0 += q0.x + q0.y + q0.z;
        a1 += q0.w + q1.x + q1.y;
        a2 += q1.z + q1.w + q2.x;
        a3 += q2.y + q2.z + q2.w;
      }
      float4* dst = reinterpret_cast<float4*>(&lds[(c*4 + ds4)*68 + orow*8 + 4*h]);
      *dst = make_float4(a0*(1.f/9.f), a1*(1.f/9.f), a2*(1.f/9.f), a3*(1.f/9.f));
    }
    __syncthreads();                   // raw(c) reads done; xds(c) visible
    if (c < 7) {
      float4* rw = reinterpret_cast<float4*>(&lds[T_RAW + s4*SSTR]);
      #pragma unroll
      for (int j = 0; j < 5; j++) rw[tin + 32*j] = pre[j];
      if (tin < 8) rw[tin + 160] = pre[5];
      __syncthreads();                 // raw(c+1) visible
    }
  }

  // ---- sample's full 8x8 tile into registers ----
  float xd[64];
  #pragma unroll
  for (int r = 0; r < 8; r++) {
    const float4* src = reinterpret_cast<const float4*>(&lds[sl*68 + r*8]);
    float4 a = src[0], bq = src[1];
    xd[r*8+0]=a.x;  xd[r*8+1]=a.y;  xd[r*8+2]=a.z;  xd[r*8+3]=a.w;
    xd[r*8+4]=bq.x; xd[r*8+5]=bq.y; xd[r*8+6]=bq.z; xd[r*8+7]=bq.w;
  }

  // ---- stage 1: 5 channels per part, full pool grid, fc rows from TAB ----
  float logits[10];
  #pragma unroll
  for (int c = 0; c < 10; c++) logits[c] = 0.0f;

  #pragma unroll 1
  for (int ci = 0; ci < 5; ci++) {
    const int ch = p*5 + ci;
    const float4* wp = reinterpret_cast<const float4*>(&lds[T_TAB + I_W1P + ch*12]);
    float4 w0 = wp[0], w1v = wp[1], w2v = wp[2];
    const float w_[9] = {w0.x,w0.y,w0.z,w0.w,w1v.x,w1v.y,w1v.z,w1v.w,w2v.x};
    const float bb = lds[T_TAB + I_B1F + ch];
    float feat[9];
    #pragma unroll
    for (int pr = 0; pr < 3; pr++) {
      #pragma unroll
      for (int pc = 0; pc < 3; pc++) {
        float c00 = bb, c01 = bb, c10 = bb, c11 = bb;
        #pragma unroll
        for (int dr = 0; dr < 3; dr++) {
          #pragma unroll
          for (int dc = 0; dc < 3; dc++) {
            float wk = w_[dr*3 + dc];
            c00 = fmaf(xd[(2*pr+0+dr)*8 + 2*pc+0+dc], wk, c00);
            c01 = fmaf(xd[(2*pr+0+dr)*8 + 2*pc+1+dc], wk, c01);
            c10 = fmaf(xd[(2*pr+1+dr)*8 + 2*pc+0+dc], wk, c10);
            c11 = fmaf(xd[(2*pr+1+dr)*8 + 2*pc+1+dc], wk, c11);
          }
        }
        feat[pr*3+pc] = fmaxf(fmaxf(fmaxf(c00, c01), fmaxf(c10, c11)), 0.0f);
      }
    }
    #pragma unroll
    for (int pp = 0; pp < 9; pp++) {
      const float4* f4r = reinterpret_cast<const float4*>(
          &lds[T_TAB + I_FCW1R + (ch*9 + pp)*12]);
      float4 f0 = f4r[0], f1 = f4r[1], f2 = f4r[2];
      const float fv = feat[pp];
      logits[0] = fmaf(fv, f0.x, logits[0]);
      logits[1] = fmaf(fv, f0.y, logits[1]);
      logits[2] = fmaf(fv, f0.z, logits[2]);
      logits[3] = fmaf(fv, f0.w, logits[3]);
      logits[4] = fmaf(fv, f1.x, logits[4]);
      logits[5] = fmaf(fv, f1.y, logits[5]);
      logits[6] = fmaf(fv, f1.z, logits[6]);
      logits[7] = fmaf(fv, f1.w, logits[7]);
      logits[8] = fmaf(fv, f2.x, logits[8]);
      logits[9] = fmaf(fv, f2.y, logits[9]);
    }
  }

  // butterfly all-reduce over the 4 parts (bit-identical on all lanes), + bias
  #pragma unroll
  for (int c = 0; c < 10; c++) {
    float v = logits[c];
    v += __shfl_xor(v, 1);
    v += __shfl_xor(v, 2);
    logits[c] = v + lds[T_TAB + I_FCB1 + c];
  }

  // ---- top-2 (stable-argsort tie semantics) ----
  int i1 = 0; float v1m = logits[0];
  #pragma unroll
  for (int c = 1; c < 10; c++) { if (logits[c] >= v1m) { v1m = logits[c]; i1 = c; } }
  int i2 = 0; float v2m = -3.0e38f;
  #pragma unroll
  for (int c = 0; c < 10; c++) { if (c != i1 && logits[c] >= v2m) { v2m = logits[c]; i2 = c; } }
  const int idx0 = i1 < i2 ? i1 : i2;
  const int idx1 = i1 < i2 ? i2 : i1;
  int eid = 8*idx0 - (idx0*(idx0-1))/2 + idx1 - 1;
  eid = eid < 0 ? 0 : (eid > 44 ? 44 : eid);

  float sume = 0.0f;
  #pragma unroll
  for (int c = 0; c < 10; c++) sume += __expf(logits[c] - v1m);
  const bool use1 = (-__logf(sume)) > 0.3f;

  // ---- stash logits (= out1) in LDS; frees 10 VGPRs across stage 2 ----
  __syncthreads();                       // all waves done reading xds region
  if (p == 0) {
    #pragma unroll
    for (int c = 0; c < 5; c++) lds[sl*10 + c] = logits[c];
  } else if (p == 1) {
    #pragma unroll
    for (int c = 5; c < 10; c++) lds[sl*10 + c] = logits[c];
  }

  // ---- stage 2: channels o = p + 4*oi, full 2x2 pool per channel ----
  const float4* W2F4 = reinterpret_cast<const float4*>(ws);
  const float4* FC24 = reinterpret_cast<const float4*>(ws + OFF_FC2);
  float s2a = 0.0f, s2b = 0.0f;

  #pragma unroll 1
  for (int oi = 0; oi < 4; oi++) {
    const int o = p + 4*oi;
    if (o < 15) {
      float4 wv[7];
      #pragma unroll
      for (int k4 = 0; k4 < 7; k4++) wv[k4] = W2F4[(o*7 + k4)*45 + eid];
      const float4 fa = FC24[o*45 + eid];
      const float4 fb = FC24[(15 + o)*45 + eid];
      const float bias = wv[6].y;        // folded BN bias (slot 25)
      float feat0 = 0.f, feat1 = 0.f, feat2 = 0.f, feat3 = 0.f;
      #pragma unroll
      for (int ph = 0; ph < 2; ph++) {
        #pragma unroll
        for (int pw = 0; pw < 2; pw++) {
          float c00 = bias, c01 = bias, c10 = bias, c11 = bias;
          #pragma unroll
          for (int i = 0; i < 5; i++) {
            #pragma unroll
            for (int j = 0; j < 5; j++) {
              float wk = GETC(wv, i*5 + j);
              c00 = fmaf(xd[(2*ph+0+i)*8 + 2*pw+0+j], wk, c00);
              c01 = fmaf(xd[(2*ph+0+i)*8 + 2*pw+1+j], wk, c01);
              c10 = fmaf(xd[(2*ph+1+i)*8 + 2*pw+0+j], wk, c10);
              c11 = fmaf(xd[(2*ph+1+i)*8 + 2*pw+1+j], wk, c11);
            }
          }
          float f = fmaxf(fmaxf(fmaxf(c00, c01), fmaxf(c10, c11)), 0.0f);
          if (ph == 0 && pw == 0) feat0 = f;
          else if (ph == 0)       feat1 = f;
          else if (pw == 0)       feat2 = f;
          else                    feat3 = f;
        }
      }
      s2a = fmaf(feat0, fa.x, fmaf(feat1, fa.y, fmaf(feat2, fa.z, fmaf(feat3, fa.w, s2a))));
      s2b = fmaf(feat0, fb.x, fmaf(feat1, fb.y, fmaf(feat2, fb.z, fmaf(feat3, fb.w, s2b))));
      s2a += wv[6].z;                    // fcb2[e][0] at o==0, exact 0 otherwise
      s2b += wv[6].w;                    // fcb2[e][1] at o==0, exact 0 otherwise
    }
  }
  s2a += __shfl_xor(s2a, 1); s2a += __shfl_xor(s2a, 2);
  s2b += __shfl_xor(s2b, 1); s2b += __shfl_xor(s2b, 2);

  // ---- scatter + log_softmax (logits from LDS stash) ----
  __syncthreads();
  float o10[10];
  #pragma unroll
  for (int c = 0; c < 10; c++) {
    float v = -100.0f;
    v = (c == idx0) ? s2a : v;
    v = (c == idx1) ? s2b : v;
    o10[c] = use1 ? lds[sl*10 + c] : v;
  }
  float m2x = o10[0];
  #pragma unroll
  for (int c = 1; c < 10; c++) m2x = fmaxf(m2x, o10[c]);
  float se2 = 0.0f;
  #pragma unroll
  for (int c = 0; c < 10; c++) se2 += __expf(o10[c] - m2x);
  const float lse2 = m2x + __logf(se2);

  // ---- stage out2 into LDS; coalesced float4 block store ----
  if (p == 2) {
    #pragma unroll
    for (int c = 0; c < 5; c++) lds[320 + sl*10 + c] = o10[c] - lse2;
  } else if (p == 3) {
    #pragma unroll
    for (int c = 5; c < 10; c++) lds[320 + sl*10 + c] = o10[c] - lse2;
  }
  __syncthreads();

  if (blockIdx.x * 32 + 32 <= B) {       // full block: coalesced path
    const float4* l4 = reinterpret_cast<const float4*>(lds);
    float4* o1 = reinterpret_cast<float4*>(out + (size_t)blockIdx.x * 320);
    float4* o2 = reinterpret_cast<float4*>(out + (size_t)B*10 + (size_t)blockIdx.x * 320);
    if (t < 80)  o1[t] = l4[t];
    if (t >= 48) o2[t - 48] = l4[80 + (t - 48)];
  } else if (valid) {                    // tail block fallback
    const size_t base = (size_t)b * 10;
    if (p == 0) {
      #pragma unroll
      for (int c = 0; c < 5; c++) out[base + c] = lds[sl*10 + c];
    } else if (p == 1) {
      #pragma unroll
      for (int c = 5; c < 10; c++) out[base + c] = lds[sl*10 + c];
    } else if (p == 2) {
      #pragma unroll
      for (int c = 0; c < 5; c++) out[(size_t)B*10 + base + c] = lds[320 + sl*10 + c];
    } else {
      #pragma unroll
      for (int c = 5; c < 10; c++) out[(size_t)B*10 + base + c] = lds[320 + sl*10 + c];
    }
  }
}

extern "C" void kernel_launch(void* const* d_in, const int* in_sizes, int n_in,
                              void* d_out, int out_size, void* d_ws, size_t ws_size,
                              hipStream_t stream) {
  const float* x    = (const float*)d_in[0];
  const float* w1   = (const float*)d_in[1];
  const float* b1   = (const float*)d_in[2];
  const float* g1   = (const float*)d_in[3];
  const float* be1  = (const float*)d_in[4];
  const float* m1   = (const float*)d_in[5];
  const float* v1   = (const float*)d_in[6];
  const float* fcw1 = (const float*)d_in[7];
  const float* fcb1 = (const float*)d_in[8];
  const float* w2   = (const float*)d_in[9];
  const float* b2   = (const float*)d_in[10];
  const float* g2   = (const float*)d_in[11];
  const float* be2  = (const float*)d_in[12];
  const float* m2   = (const float*)d_in[13];
  const float* v2   = (const float*)d_in[14];
  const float* fcw2 = (const float*)d_in[15];
  const float* fcb2 = (const float*)d_in[16];
  float* out = (float*)d_out;
  float* ws  = (float*)d_ws;
  const int B = in_sizes[0] / 784;

  setup_tables<<<80, 256, 0, stream>>>(w1, b1, g1, be1, m1, v1,
                                       w2, b2, g2, be2, m2, v2,
                                       fcw2, fcb2, fcw1, fcb1, ws);
  fused_k<<<(B + 31)/32, 128, 0, stream>>>(x, ws, out, B);
}